// Round 3
// baseline (224.545 us; speedup 1.0000x reference)
//
#include <hip/hip_runtime.h>

// PlateYoloBlock: (32,13,256,256) fp32 -> (32,65536,13) fp32
// out[b][y*256+x][c]:
//   c=0: (sigmoid(v)+x)*8   c=1: (sigmoid(v)+y)*8
//   c=2,3: exp(v)*8         c=4..11: v*8          c=12: sigmoid(v)
//
// R3: R1/R2 both stuck at 65 us (5.4 B/cyc/CU) despite different load widths
// and occupancy -> the shared load/barrier/store phase-lock is the suspect.
// This version: NO LDS, NO barrier. Register transpose; stores are 13 x
// dwordx4 per thread at 208 B lane stride (each wave still covers one
// contiguous 13 KiB output region -> L2 merges to full lines).

#define NB      32
#define NC      13
#define HW      65536     // 256*256 positions per batch
#define WIDTH   256
#define TILE    1024      // positions per block
#define THREADS 256       // 4 consecutive positions per thread

__device__ __forceinline__ float sigmoidf_(float x) {
    return 1.0f / (1.0f + __expf(-x));
}

__global__ __launch_bounds__(THREADS) void plate_yolo_kernel(
        const float* __restrict__ in, float* __restrict__ out) {
    const int tid = threadIdx.x;
    const long long s0 = (long long)blockIdx.x * TILE;   // global spatial base
    const int b = (int)(s0 >> 16);                       // 65536 positions/batch
    const int posBase = (int)(s0 & (HW - 1));
    const float* __restrict__ inB = in + (long long)b * NC * HW + posBase;

    // ---- 13 independent coalesced dwordx4 loads (4 positions/thread)
    const int p4 = tid * 4;
    float4 v[NC];
    #pragma unroll
    for (int c = 0; c < NC; ++c)
        v[c] = *(const float4*)(inB + c * HW + p4);

    // positions p4..p4+3 never cross an image row (p4 % 4 == 0, row = 256)
    const int pos = posBase + p4;
    const float fx0 = (float)(pos & (WIDTH - 1));
    const float fy  = (float)(pos >> 8);

    // ---- pointwise math + in-register transpose to output order [j][c]
    __align__(16) float o[4 * NC];
    #pragma unroll
    for (int j = 0; j < 4; ++j) {
        const float x = fx0 + (float)j;
        #pragma unroll
        for (int c = 0; c < NC; ++c) {
            const float val = ((const float*)&v[c])[j];
            float r;
            if (c == 0)                 r = (sigmoidf_(val) + x) * 8.0f;
            else if (c == 1)            r = (sigmoidf_(val) + fy) * 8.0f;
            else if (c == 2 || c == 3)  r = __expf(val) * 8.0f;
            else if (c == 12)           r = sigmoidf_(val);
            else                        r = val * 8.0f;
            o[j * NC + c] = r;
        }
    }

    // ---- 13 x global_store_dwordx4, lane stride 208 B (16B aligned).
    // Wave covers contiguous [waveBase, waveBase + 13312) bytes; every 64B
    // line is fully written across the 13 instructions -> L2 write-combine.
    float4* __restrict__ dst = (float4*)(out + s0 * NC + (long long)tid * (4 * NC));
    #pragma unroll
    for (int q = 0; q < NC; ++q)
        dst[q] = *(const float4*)&o[4 * q];
}

extern "C" void kernel_launch(void* const* d_in, const int* in_sizes, int n_in,
                              void* d_out, int out_size, void* d_ws, size_t ws_size,
                              hipStream_t stream) {
    const float* in = (const float*)d_in[0];
    float* out = (float*)d_out;
    const int blocks = (NB * HW) / TILE;   // 2048
    plate_yolo_kernel<<<blocks, THREADS, 0, stream>>>(in, out);
}

// Round 4
// 193.992 us; speedup vs baseline: 1.1575x; 1.1575x over previous
//
#include <hip/hip_runtime.h>

// PlateYoloBlock: (32,13,256,256) fp32 -> (32,65536,13) fp32
// out[b][y*256+x][c]:
//   c=0: (sigmoid(v)+x)*8   c=1: (sigmoid(v)+y)*8
//   c=2,3: exp(v)*8         c=4..11: v*8          c=12: sigmoid(v)
//
// R4: wave-autonomous version. R1/R2's __syncthreads phase-locked the whole
// device into alternating read-bursts / write-bursts (both stuck at 65 us,
// 2.45 TB/s, while fillBuffer does 6.7). Here each wave transposes through
// its PRIVATE LDS slab -> only in-wave lgkmcnt ordering, no barrier, waves
// drift into anti-phase -> steady mixed r/w stream. Loads and stores both
// stay fully coalesced dwordx4.

#define NB      32
#define NC      13
#define HW      65536     // 256*256 positions per batch
#define WIDTH   256
#define WTILE   256       // positions per wave-tile (4 per lane)
#define TPW     2         // tiles per wave
#define WAVES   2         // waves per block
#define THREADS (WAVES * 64)

__device__ __forceinline__ float sigmoidf_(float x) {
    return 1.0f / (1.0f + __expf(-x));
}

__global__ __launch_bounds__(THREADS) void plate_yolo_kernel(
        const float* __restrict__ in, float* __restrict__ out) {
    // one private 13,312 B slab per wave; 26,624 B total -> 6 blocks/CU
    __shared__ __align__(16) float lds[WAVES][WTILE * NC];

    const int lane = threadIdx.x & 63;
    const int wid  = threadIdx.x >> 6;
    float* slab = lds[wid];

    #pragma unroll
    for (int s = 0; s < TPW; ++s) {
        // wave-tile id; each wave owns TPW consecutive tiles (26.6 KB contig)
        const int T = blockIdx.x * (WAVES * TPW) + wid * TPW + s;
        const int b = T >> 8;                        // 256 tiles per batch
        const int posBase = (T & 255) * WTILE;       // position within batch
        const float* __restrict__ inB = in + (size_t)b * NC * HW + posBase;
        const int p4 = lane * 4;

        // 13 independent coalesced dwordx4 loads (1 KiB/wave/instr)
        float4 v[NC];
        #pragma unroll
        for (int c = 0; c < NC; ++c)
            v[c] = *(const float4*)(inB + c * HW + p4);

        // group of 4 positions never crosses an image row (p4 % 4 == 0)
        const int pos = posBase + p4;
        const float fx0 = (float)(pos & (WIDTH - 1));
        const float fy  = (float)(pos >> 8);

        // pointwise math + register transpose to output order [j][c]
        __align__(16) float o[4 * NC];
        #pragma unroll
        for (int j = 0; j < 4; ++j) {
            const float x = fx0 + (float)j;
            #pragma unroll
            for (int c = 0; c < NC; ++c) {
                const float val = ((const float*)&v[c])[j];
                float r;
                if (c == 0)                 r = (sigmoidf_(val) + x) * 8.0f;
                else if (c == 1)            r = (sigmoidf_(val) + fy) * 8.0f;
                else if (c == 2 || c == 3)  r = __expf(val) * 8.0f;
                else if (c == 12)           r = sigmoidf_(val);
                else                        r = val * 8.0f;
                o[j * NC + c] = r;
            }
        }

        // 13 x ds_write_b128, lane stride 208 B: lanes 0..7 start at banks
        // {0,20,8,28,16,4,24,12} covering all 32 banks -> 8 conflict-free
        // phases (the b128 structural minimum).
        float4* wslab = (float4*)(slab + lane * (4 * NC));
        #pragma unroll
        for (int q = 0; q < NC; ++q)
            wslab[q] = *(const float4*)&o[4 * q];

        // wave-private slab: compiler's lgkmcnt ordering suffices, NO barrier.
        // contiguous ds_read_b128 + global_store_dwordx4 (1 KiB/wave/instr)
        const float4* __restrict__ src = (const float4*)slab;
        float4* __restrict__ dst = (float4*)(out + (size_t)T * (WTILE * NC));
        #pragma unroll
        for (int q = 0; q < NC; ++q)
            dst[q * 64 + lane] = src[q * 64 + lane];
    }
}

extern "C" void kernel_launch(void* const* d_in, const int* in_sizes, int n_in,
                              void* d_out, int out_size, void* d_ws, size_t ws_size,
                              hipStream_t stream) {
    const float* in = (const float*)d_in[0];
    float* out = (float*)d_out;
    // total wave-tiles = NB*HW/WTILE = 8192; per block = WAVES*TPW = 4
    const int blocks = (NB * HW / WTILE) / (WAVES * TPW);   // 2048
    plate_yolo_kernel<<<blocks, THREADS, 0, stream>>>(in, out);
}